// Round 5
// baseline (429.108 us; speedup 1.0000x reference)
//
#include <hip/hip_runtime.h>
#include <hip/hip_bf16.h>
#include <cstdint>
#include <cstddef>

// ---------------------------------------------------------------------------
// SelfAttention b=2, s=2048, H=8, K=512.
// 8-phase counted-vmcnt GEMM engine (T2+T3+T4+T5), 256^2 tiles, BK=64 as
// 2 k-slabs of 32, 4-slab LDS ring per operand (128 KiB), 8 waves.
// mm8<0>: Q/K proj  mm8<1>: V proj (transposed Vt)  mm8<2>: causal S (exp+
// row-sum l, packed padded-triangular P)  mm8<3>: PV (x 1/l).
// Final 512-col projection stays 2-phase (memory-bound, K=4096).
// ws (MB): 0-4 Wu | 4 lR | 5-37 Q(->HO) | 37-69 K(->Vt) | 69-141 Sp
//          (wqb 69-73, wkb 73-77 dead before S) ; xb/wvb live in d_out.
// ---------------------------------------------------------------------------

typedef __bf16 bf16;
typedef __bf16 bf16x8 __attribute__((ext_vector_type(8)));
typedef float  f32x4  __attribute__((ext_vector_type(4)));
typedef unsigned short u16x4 __attribute__((ext_vector_type(4)));

__device__ __forceinline__ void gl2lds16(const void* g, void* l) {
  __builtin_amdgcn_global_load_lds(
      (const __attribute__((address_space(1))) unsigned int*)g,
      (__attribute__((address_space(3))) unsigned int*)l, 16, 0, 0);
}

__device__ __forceinline__ unsigned short bfbits(float f) {
  return __builtin_bit_cast(unsigned short, (__bf16)f);
}

// ---------------------------------------------------------------------------
// Kernel 1: fp32 -> bf16 for x, Wq, Wk, Wv, Wu (each 2^21 elements)
// ---------------------------------------------------------------------------
__global__ __launch_bounds__(256) void cvt_all(
    const float* __restrict__ x,  const float* __restrict__ wq,
    const float* __restrict__ wk, const float* __restrict__ wv,
    const float* __restrict__ wu,
    bf16* __restrict__ xb,  bf16* __restrict__ wqb, bf16* __restrict__ wkb,
    bf16* __restrict__ wvb, bf16* __restrict__ wub)
{
  const int Q4 = (1 << 21) / 4;
  int i = blockIdx.x * 256 + threadIdx.x;
  int a = i / Q4;
  int off = (i - a * Q4) * 4;
  const float* s; bf16* d;
  switch (a) {
    case 0: s = x;  d = xb;  break;
    case 1: s = wq; d = wqb; break;
    case 2: s = wk; d = wkb; break;
    case 3: s = wv; d = wvb; break;
    default: s = wu; d = wub; break;
  }
  float4 v = *(const float4*)(s + off);
  u16x4 o = { bfbits(v.x), bfbits(v.y), bfbits(v.z), bfbits(v.w) };
  *(u16x4*)(d + off) = o;
}

// ---------------------------------------------------------------------------
// 8-phase engine. Slab = 256 rows x 32 k (16 KB), ring of 4 per operand.
// Tile u (BK=64) = slabs kh0,kh1 at ring slot (2u+kh)&3.  Per phase: read one
// 4-frag A subtile (+B on kh entry), stage 1 slab, barrier, 16 MFMA, vmcnt(8),
// barrier.  Ledger: every read's slab is >=4 slabs old at its covering check.
// ---------------------------------------------------------------------------
#define RD_A(AS, FI0)                                                       \
  { _Pragma("unroll") for (int i_ = 0; i_ < 4; ++i_)                        \
      afr[i_] = *(const bf16x8*)&sm[(AS) * 8192 + aoff[(FI0) + i_]]; }
#define RD_B(BS)                                                            \
  { _Pragma("unroll") for (int j_ = 0; j_ < 4; ++j_)                        \
      bfr[j_] = *(const bf16x8*)&sm[32768 + (BS) * 8192 + boff[j_]]; }
#define MF16(FI0)                                                           \
  { _Pragma("unroll") for (int i_ = 0; i_ < 4; ++i_)                        \
      _Pragma("unroll") for (int j_ = 0; j_ < 4; ++j_)                      \
        acc[(FI0) + i_][j_] = __builtin_amdgcn_mfma_f32_16x16x32_bf16(      \
            afr[i_], bfr[j_], acc[(FI0) + i_][j_], 0, 0, 0); }
#define PH(AS, BS, FI0, DOB, STG)                                           \
  {                                                                         \
    if (DOB) RD_B(BS);                                                      \
    RD_A(AS, FI0);                                                          \
    STG;                                                                    \
    __builtin_amdgcn_s_barrier();                                           \
    __builtin_amdgcn_s_setprio(1);                                          \
    MF16(FI0);                                                              \
    __builtin_amdgcn_s_setprio(0);                                          \
    asm volatile("s_waitcnt vmcnt(8)" ::: "memory");                        \
    __builtin_amdgcn_sched_barrier(0);                                      \
    __builtin_amdgcn_s_barrier();                                           \
    __builtin_amdgcn_sched_barrier(0);                                      \
  }

template<int MODE>
__global__ __launch_bounds__(512, 2)
void mm8(const bf16* __restrict__ Ag, const bf16* __restrict__ Bg,
         void* __restrict__ Cp, float* __restrict__ lptr)
{
  __shared__ __align__(16) bf16 sm[65536];   // 128 KiB: A ring | B ring
  __shared__ float sInv[256];

  const int tid = threadIdx.x, w = tid >> 6, lane = tid & 63;
  const int g = lane >> 4, c16 = lane & 15;
  const int wr = w >> 2, wc = w & 3;

  int nt = 8;
  const bf16 *Ab = Ag, *Bb = Bg;
  int m0 = 0, n0 = 0, bh = 0, TM = 0, TN = 0, T = 0, nd = 0;
  size_t rowBase0 = 0, rowBase1 = 0;

  if constexpr (MODE <= 1) {
    const int wg = ((blockIdx.x & 7) << 5) | (blockIdx.x >> 3);
    m0 = (wg >> 4) * 256; n0 = (wg & 15) * 256;
    Ab = Ag + (size_t)m0 * 512;
    Bb = Bg + (size_t)n0 * 512;
  } else if constexpr (MODE == 2) {
    const int wg = (blockIdx.x & 7) * 72 + (blockIdx.x >> 3);
    bh = wg / 36; int t = wg % 36;
    TM = 0;
    while ((TM + 1) * (TM + 2) / 2 <= t) TM++;
    TN = t - TM * (TM + 1) / 2;
    const int b = bh >> 3, h = bh & 7;
    Ab = Ag + (size_t)(b * 2048 + TM * 256) * 4096 + h * 512;
    Bb = Bg + (size_t)(b * 2048 + TN * 256) * 4096 + h * 512;
  } else {
    const int wg = ((blockIdx.x & 7) << 5) | (blockIdx.x >> 3);
    bh = wg >> 4; const int r = wg & 15;
    T = 7 - (r >> 1); nd = r & 1;
    rowBase0 = (size_t)bh * 144 + (size_t)(2 * T) * (T + 1);
    rowBase1 = rowBase0 + (2 * T + 2);
    Bb = Bg + (size_t)(bh * 512 + nd * 256) * 2048;
    nt = 4 * (T + 1);
    if (tid < 256) sInv[tid] = 1.0f / lptr[bh * 2048 + T * 256 + tid];
  }

  // per-thread fragment LDS offsets (swizzle folded in; thread-constant)
  int aoff[8], boff[4];
  #pragma unroll
  for (int i = 0; i < 8; ++i) {
    int row = wr * 128 + i * 16 + c16;
    aoff[i] = row * 32 + ((g ^ ((row >> 1) & 3)) << 3);
  }
  #pragma unroll
  for (int j = 0; j < 4; ++j) {
    int row = wc * 64 + j * 16 + c16;
    boff[j] = row * 32 + ((g ^ ((row >> 1) & 3)) << 3);
  }

  f32x4 z = {0.f, 0.f, 0.f, 0.f};
  f32x4 acc[8][4];
  #pragma unroll
  for (int i = 0; i < 8; i++)
    #pragma unroll
    for (int j = 0; j < 4; j++) acc[i][j] = z;

  auto stgA = [&](int slot, int u, int kh) {
    #pragma unroll
    for (int r2 = 0; r2 < 2; ++r2) {
      int c = (r2 << 9) + tid;
      int row = c >> 2, cb = c & 3;
      int ke = u * 64 + kh * 32 + ((cb ^ ((row >> 1) & 3)) << 3);
      const bf16* src;
      if constexpr (MODE <= 1)      src = Ab + (size_t)row * 512 + ke;
      else if constexpr (MODE == 2) src = Ab + (size_t)row * 4096 + ke;
      else {
        size_t tb = (row < 128 ? rowBase0 : rowBase1) + (ke >> 7);
        src = Ag + tb * 16384 + (size_t)(row & 127) * 128 + (ke & 127);
      }
      gl2lds16(src, &sm[slot * 8192 + c * 8]);
    }
  };
  auto stgB = [&](int slot, int u, int kh) {
    #pragma unroll
    for (int r2 = 0; r2 < 2; ++r2) {
      int c = (r2 << 9) + tid;
      int row = c >> 2, cb = c & 3;
      int ke = u * 64 + kh * 32 + ((cb ^ ((row >> 1) & 3)) << 3);
      const bf16* src;
      if constexpr (MODE <= 1)      src = Bb + (size_t)row * 512 + ke;
      else if constexpr (MODE == 2) src = Bb + (size_t)row * 4096 + ke;
      else                          src = Bb + (size_t)row * 2048 + ke;
      gl2lds16(src, &sm[32768 + slot * 8192 + c * 8]);
    }
  };

  // prologue: tile0 (both slabs) + tile1.k0 ; first 2 slabs must land
  stgA(0, 0, 0); stgB(0, 0, 0);
  stgA(1, 0, 1); stgB(1, 0, 1);
  stgA(2, 1, 0); stgB(2, 1, 0);
  asm volatile("s_waitcnt vmcnt(8)" ::: "memory");
  __builtin_amdgcn_s_barrier();
  __builtin_amdgcn_sched_barrier(0);

  bf16x8 afr[4], bfr[4];
  const int half = nt >> 1;
  for (int ii = 0; ii < half; ++ii) {
    const int t = ii << 1;
    const bool s2 = (t + 2 < nt), s3 = (t + 3 < nt);
    PH(0,  0, 0, true,  stgA(3, t + 1, 1))                    // p1: tile t  kh0
    PH(0, -1, 4, false, stgB(3, t + 1, 1))                    // p2
    PH(1,  1, 0, true,  if (s2) stgA(0, t + 2, 0))            // p3: tile t  kh1
    PH(1, -1, 4, false, if (s2) stgB(0, t + 2, 0))            // p4
    PH(2,  2, 0, true,  if (s2) stgA(1, t + 2, 1))            // p5: tile t+1 kh0
    PH(2, -1, 4, false, if (s2) stgB(1, t + 2, 1))            // p6
    PH(3,  3, 0, true,  if (s3) stgA(2, t + 3, 0))            // p7: tile t+1 kh1
    PH(3, -1, 4, false, if (s3) stgB(2, t + 3, 0))            // p8
  }
  __syncthreads();   // full drain before LDS reuse as epilogue buffer

  if constexpr (MODE == 0) {
    bf16* C = (bf16*)Cp;
    bf16* ep = sm;
    #pragma unroll
    for (int hp = 0; hp < 2; ++hp) {
      if (wr == hp) {
        #pragma unroll
        for (int i = 0; i < 8; i++) {
          int rl = i * 16 + g * 4;
          #pragma unroll
          for (int j = 0; j < 4; j++) {
            int cl = wc * 64 + j * 16 + c16;
            #pragma unroll
            for (int jj = 0; jj < 4; jj++)
              ep[(rl + jj) * 264 + cl] = (bf16)acc[i][j][jj];
          }
        }
      }
      __syncthreads();
      {
        int r = tid >> 2, ch = tid & 3;
        const bf16* src = &ep[r * 264 + ch * 64];
        bf16* dst = C + (size_t)(m0 + hp * 128 + r) * 4096 + n0 + ch * 64;
        #pragma unroll
        for (int q = 0; q < 8; q++)
          *(bf16x8*)(dst + q * 8) = *(const bf16x8*)(src + q * 8);
      }
      if (hp == 0) __syncthreads();
    }
  } else if constexpr (MODE == 1) {
    // Vt[(bb*4096 + n)*2048 + srow]
    bf16* C = (bf16*)Cp;
    bf16* ep = sm;
    #pragma unroll
    for (int hp = 0; hp < 2; ++hp) {
      if (wr == hp) {
        #pragma unroll
        for (int i = 0; i < 8; i++) {
          int rl = i * 16 + g * 4;
          #pragma unroll
          for (int j = 0; j < 4; j++) {
            int cl = wc * 64 + j * 16 + c16;
            u16x4 pk = { bfbits(acc[i][j][0]), bfbits(acc[i][j][1]),
                         bfbits(acc[i][j][2]), bfbits(acc[i][j][3]) };
            *(u16x4*)&ep[cl * 136 + rl] = pk;
          }
        }
      }
      __syncthreads();
      {
        int cl = tid >> 1, rc = tid & 1;
        const bf16* src = &ep[cl * 136 + rc * 64];
        int mg = m0 + hp * 128 + rc * 64;
        int bb = mg >> 11, srow = mg & 2047;
        bf16* dst = C + ((size_t)(bb * 4096 + n0 + cl)) * 2048 + srow;
        #pragma unroll
        for (int q = 0; q < 8; q++)
          *(bf16x8*)(dst + q * 8) = *(const bf16x8*)(src + q * 8);
      }
      if (hp == 0) __syncthreads();
    }
  } else if constexpr (MODE == 2) {
    // P = exp2(S*sc), packed padded-triangular tiles + f32 row sums
    const float SC2 = 0.044194173824159216f * 1.4426950408889634f;
    bf16* ep = sm;
    float rsum[8][4];
    #pragma unroll
    for (int i = 0; i < 8; i++)
      #pragma unroll
      for (int jj = 0; jj < 4; jj++) rsum[i][jj] = 0.f;

    #pragma unroll
    for (int hp = 0; hp < 2; ++hp) {
      if (wr == hp) {
        #pragma unroll
        for (int i = 0; i < 8; i++) {
          #pragma unroll
          for (int j = 0; j < 4; j++) {
            int cl = wc * 64 + j * 16 + c16;
            int kglob = TN * 256 + cl;
            #pragma unroll
            for (int jj = 0; jj < 4; jj++) {
              int rl = i * 16 + g * 4 + jj;
              int qglob = TM * 256 + hp * 128 + rl;
              float p = (kglob <= qglob) ? exp2f(acc[i][j][jj] * SC2) : 0.f;
              rsum[i][jj] += p;
              ep[rl * 264 + cl] = (bf16)p;
            }
          }
        }
      }
      __syncthreads();
      {
        int r = tid >> 2, ch = tid & 3;
        int tm128 = 2 * TM + hp, tn128 = 2 * TN + (ch >> 1);
        bool wrOK = (tn128 <= tm128) || (hp == 0 && tn128 == tm128 + 1);
        if (wrOK) {
          const bf16* src = &ep[r * 264 + ch * 64];
          size_t toff = (size_t)bh * 144 + (size_t)(2 * TM) * (TM + 1)
                      + (size_t)hp * (2 * TM + 2) + tn128;
          bf16* dst = (bf16*)Cp + toff * 16384 + r * 128 + (ch & 1) * 64;
          #pragma unroll
          for (int q = 0; q < 8; q++)
            *(bf16x8*)(dst + q * 8) = *(const bf16x8*)(src + q * 8);
        }
      }
      if (hp == 0) __syncthreads();
    }
    #pragma unroll
    for (int i = 0; i < 8; i++)
      #pragma unroll
      for (int jj = 0; jj < 4; jj++) {
        float v = rsum[i][jj];
        v += __shfl_xor(v, 1);
        v += __shfl_xor(v, 2);
        v += __shfl_xor(v, 4);
        v += __shfl_xor(v, 8);
        if (c16 == 0) {
          int qglob = TM * 256 + wr * 128 + i * 16 + g * 4 + jj;
          atomicAdd(&lptr[bh * 2048 + qglob], v);
        }
      }
  } else {
    // PV: scale by 1/l, write HO
    const int b = bh >> 3, h = bh & 7;
    bf16* Cb = (bf16*)Cp + (size_t)(b * 2048 + T * 256) * 4096
             + h * 512 + nd * 256;
    bf16* ep = sm;
    #pragma unroll
    for (int hp = 0; hp < 2; ++hp) {
      if (wr == hp) {
        #pragma unroll
        for (int i = 0; i < 8; i++) {
          #pragma unroll
          for (int j = 0; j < 4; j++) {
            int cl = wc * 64 + j * 16 + c16;
            #pragma unroll
            for (int jj = 0; jj < 4; jj++) {
              int rl = i * 16 + g * 4 + jj;
              ep[rl * 264 + cl] = (bf16)(acc[i][j][jj] * sInv[hp * 128 + rl]);
            }
          }
        }
      }
      __syncthreads();
      {
        int r = tid >> 2, ch = tid & 3;
        const bf16* src = &ep[r * 264 + ch * 64];
        bf16* dst = Cb + (size_t)(hp * 128 + r) * 4096 + ch * 64;
        #pragma unroll
        for (int q = 0; q < 8; q++)
          *(bf16x8*)(dst + q * 8) = *(const bf16x8*)(src + q * 8);
      }
      if (hp == 0) __syncthreads();
    }
  }
}

// ---------------------------------------------------------------------------
// Final projection: C[4096,512] f32 = HO[4096,4096] * Wu[512,4096]^T.
// 2-phase 64x128 tile (memory-bound, K=4096), LDS-restaged f32 epilogue.
// ---------------------------------------------------------------------------
__global__ __launch_bounds__(128)
void proj_gemm(const bf16* __restrict__ A, const bf16* __restrict__ B,
               float* __restrict__ C)
{
  constexpr int BK = 32;
  constexpr int STG = 2 * 192 * BK;       // 12288 bf16
  constexpr int EPE = 64 * 132 * 2;       // 16896 bf16-equiv (f32 [64][132])
  __shared__ __align__(16) bf16 smem[EPE > STG ? EPE : STG];

  const int tid = threadIdx.x, w = tid >> 6, lane = tid & 63;
  const int g = lane >> 4, c16 = lane & 15;
  const int wg = ((blockIdx.x & 7) << 5) | (blockIdx.x >> 3);
  const int bm = wg >> 2, bn = wg & 3;
  const int m0 = bm * 64, n0 = bn * 128;
  const int wc = w;   // 2 waves, wr = 0

  f32x4 z = {0.f, 0.f, 0.f, 0.f};
  f32x4 acc[4][4];
  #pragma unroll
  for (int i = 0; i < 4; i++)
    #pragma unroll
    for (int j = 0; j < 4; j++) acc[i][j] = z;

  auto stage = [&](int buf, int kt) {
    bf16* la = &smem[buf * 192 * BK];
    #pragma unroll
    for (int r = 0; r < 2; r++) {
      int c = r * 128 + tid;
      int row = c >> 2, p = c & 3, s = p ^ ((row >> 1) & 3);
      gl2lds16(A + (size_t)(m0 + row) * 4096 + (size_t)kt * BK + s * 8,
               la + (r * 128 + w * 64) * 8);
    }
    bf16* lb = &smem[buf * 192 * BK + 64 * BK];
    #pragma unroll
    for (int r = 0; r < 4; r++) {
      int c = r * 128 + tid;
      int row = c >> 2, p = c & 3, s = p ^ ((row >> 1) & 3);
      gl2lds16(B + (size_t)(n0 + row) * 4096 + (size_t)kt * BK + s * 8,
               lb + (r * 128 + w * 64) * 8);
    }
  };

  stage(0, 0);
  __syncthreads();
  int cur = 0;
  for (int kt = 0; kt < 128; ++kt) {
    if (kt + 1 < 128) stage(cur ^ 1, kt + 1);
    const bf16* lA = &smem[cur * 192 * BK];
    const bf16* lB = &smem[cur * 192 * BK + 64 * BK];
    bf16x8 af[4], bfv[4];
    #pragma unroll
    for (int i = 0; i < 4; i++) {
      int ra = i * 16 + c16;
      af[i] = *(const bf16x8*)&lA[ra * BK + ((g ^ ((ra >> 1) & 3)) * 8)];
      int rb = wc * 64 + i * 16 + c16;
      bfv[i] = *(const bf16x8*)&lB[rb * BK + ((g ^ ((rb >> 1) & 3)) * 8)];
    }
    #pragma unroll
    for (int i = 0; i < 4; i++)
      #pragma unroll
      for (int j = 0; j < 4; j++)
        acc[i][j] = __builtin_amdgcn_mfma_f32_16x16x32_bf16(af[i], bfv[j],
                                                            acc[i][j], 0, 0, 0);
    __syncthreads();
    cur ^= 1;
  }

  float* ep = (float*)smem;
  #pragma unroll
  for (int i = 0; i < 4; i++) {
    int rl = i * 16 + g * 4;
    #pragma unroll
    for (int j = 0; j < 4; j++) {
      int cl = wc * 64 + j * 16 + c16;
      #pragma unroll
      for (int jj = 0; jj < 4; jj++)
        ep[(rl + jj) * 132 + cl] = acc[i][j][jj];
    }
  }
  __syncthreads();
  {
    int r = tid >> 1, ch = tid & 1;
    const float* src = &ep[r * 132 + ch * 64];
    float* dst = C + (size_t)(m0 + r) * 512 + n0 + ch * 64;
    #pragma unroll
    for (int q = 0; q < 16; q++)
      *(float4*)(dst + q * 4) = *(const float4*)(src + q * 4);
  }
}

// ---------------------------------------------------------------------------
extern "C" void kernel_launch(void* const* d_in, const int* in_sizes, int n_in,
                              void* d_out, int out_size, void* d_ws,
                              size_t ws_size, hipStream_t stream)
{
  (void)in_sizes; (void)n_in; (void)out_size; (void)ws_size;
  const float* x  = (const float*)d_in[0];
  const float* wq = (const float*)d_in[1];
  const float* wk = (const float*)d_in[2];
  const float* wv = (const float*)d_in[3];
  const float* wu = (const float*)d_in[4];

  char* ws = (char*)d_ws;
  const size_t MB = 1024 * 1024;
  bf16*  wub = (bf16*)(ws + 0 * MB);
  float* lR  = (float*)(ws + 4 * MB);   // 16*2048 f32 row sums
  bf16*  Qb  = (bf16*)(ws + 5 * MB);    // [4096][4096]; later HO
  bf16*  Kbf = (bf16*)(ws + 37 * MB);   // [4096][4096]; later Vt
  bf16*  Sp  = (bf16*)(ws + 69 * MB);   // packed P, 16*144 tiles = 72 MB
  bf16*  wqb = (bf16*)(ws + 69 * MB);   // dead before S
  bf16*  wkb = (bf16*)(ws + 73 * MB);   // dead before S
  bf16*  xb  = (bf16*)d_out;            // 4 MB; dead before final GEMM
  bf16*  wvb = (bf16*)d_out + (1 << 21);// 4 MB; dead before final GEMM
  bf16*  Vtb = Kbf;                     // K dead after S
  bf16*  HOb = Qb;                      // Q dead after S

  hipMemsetAsync(lR, 0, 16 * 2048 * sizeof(float), stream);
  hipLaunchKernelGGL(cvt_all, dim3(10240), dim3(256), 0, stream,
                     x, wq, wk, wv, wu, xb, wqb, wkb, wvb, wub);
  hipLaunchKernelGGL((mm8<0>), dim3(256), dim3(512), 0, stream,
                     xb, wqb, (void*)Qb, nullptr);
  hipLaunchKernelGGL((mm8<0>), dim3(256), dim3(512), 0, stream,
                     xb, wkb, (void*)Kbf, nullptr);
  hipLaunchKernelGGL((mm8<2>), dim3(576), dim3(512), 0, stream,
                     Qb, Kbf, (void*)Sp, lR);
  hipLaunchKernelGGL((mm8<1>), dim3(256), dim3(512), 0, stream,
                     xb, wvb, (void*)Vtb, nullptr);
  hipLaunchKernelGGL((mm8<3>), dim3(256), dim3(512), 0, stream,
                     Sp, Vtb, (void*)HOb, lR);
  hipLaunchKernelGGL(proj_gemm, dim3(256), dim3(128), 0, stream,
                     HOb, wub, (float*)d_out);
}